// Round 6
// baseline (257.812 us; speedup 1.0000x reference)
//
#include <hip/hip_runtime.h>
#include <stdint.h>

// Cost-volume / correlation layer, fp32.
// out[b, dy*9+dx, h, w] = (1/C) * sum_c first[b,c,h,w] * second[b,c,h+dy-4,w+dx-4]
// (zero outside bounds).  B=8, C=128, H=W=128, search_range=4 -> 81 offsets.
//
// Round-6: R2/R3/R5 all pinned at 127-135us: 128 serial channel iterations,
// each exposing one L2/L3 round-trip (compiler keeps <=1 load batch in
// flight; R5's per-channel barrier forces vmcnt(0) on the just-issued
// prefetch).  Fix = m97 mechanism: global_load_lds width-16 (unsinkable,
// vmcnt-tracked), staged in chunks of CK=4 channels, double-buffered, ONE
// barrier per chunk; chunk k+1's loads age ~500cyc under chunk k's compute
// before the barrier drain -> exposed latency ~0.  All halo sharing is
// intra-wave (TY=4, 2-wave blocks) so barriers are cheap.  XCD swizzle kept.

constexpr int B = 8, C = 128, H = 128, W = 128;
constexpr int RNG = 4, MO = 9;   // search range, max_offset = 2*RNG+1
constexpr int RW  = 4;           // pixels per thread along w
constexpr int TY  = 4;           // pixel rows per block
constexpr int CK  = 4;           // channels per staged chunk
constexpr int NCK = C / CK;      // 32 chunks
constexpr int SROW = TY * 128 + 8;  // s-channel stride (floats): 512 data + 8 pad

__device__ __forceinline__ void gl2lds16(const float* g, float* l) {
    __builtin_amdgcn_global_load_lds(
        (const __attribute__((address_space(1))) void*)g,
        (__attribute__((address_space(3))) void*)l, 16, 0, 0);
}

__global__ __launch_bounds__(128) void corr_kernel(
    const float* __restrict__ first,
    const float* __restrict__ second,
    float* __restrict__ out)
{
    // XCD-aware decode: all 9 dy of a (b,htile) pair land on one XCD's L2.
    const int lin   = blockIdx.x;          // 0..2303
    const int xcd   = lin & 7;
    const int slot  = lin >> 3;            // 0..287
    const int dy    = slot % MO;
    const int pr    = slot / MO;           // 0..31
    const int pair  = xcd * 32 + pr;       // 0..255
    const int b     = pair >> 5;
    const int htile = pair & 31;

    const int tx = threadIdx.x;            // 0..31
    const int ty = threadIdx.y;            // 0..3
    const int h0 = htile * TY;
    const int h  = h0 + ty;
    const int w0 = tx * RW;                // 0..124

    // f: [buf][ck][4 rows x 128]   (read own row only)
    // s: [buf][4 guard + ck*SROW]  (rows contiguous per channel, 8-float pad
    //    between channels absorbs the +/-4-col halo reads; masked lanes
    //    never consume the garbage)
    __shared__ float f_lds[2][CK][TY * 128];
    __shared__ float s_lds[2][4 + CK * SROW + 4];

    float acc[MO][RW];
#pragma unroll
    for (int dx = 0; dx < MO; ++dx)
#pragma unroll
        for (int p = 0; p < RW; ++p) acc[dx][p] = 0.0f;

    const size_t HW = (size_t)H * W;
    const float* fbase = first + ((size_t)b * C) * HW + (size_t)h * W + w0;

    const int  sr  = h + dy - RNG;
    const bool srv = (sr >= 0) && (sr < H);
    const float* sbase = second + ((size_t)b * C) * HW
                                + (size_t)(srv ? sr : 0) * W + w0;

    // Wave-uniform LDS staging base: wave covers ty = {2wv, 2wv+1};
    // lane l writes base + 16*l  ->  rows must be contiguous 128-float.
    const int wv2 = ty & ~1;               // 0 or 2, uniform per wave
    const float4 zero4 = make_float4(0.f, 0.f, 0.f, 0.f);

#define STAGE(K, BF)                                                        \
    {                                                                       \
        const int c0 = (K) * CK;                                            \
        _Pragma("unroll")                                                   \
        for (int j = 0; j < CK; ++j) {                                      \
            const size_t off = (size_t)(c0 + j) * HW;                       \
            gl2lds16(fbase + off, &f_lds[BF][j][wv2 * 128]);                \
            if (srv) {                                                      \
                gl2lds16(sbase + off, &s_lds[BF][4 + j * SROW + wv2 * 128]);\
            } else {                                                        \
                *(float4*)&s_lds[BF][4 + j * SROW + ty * 128 + w0] = zero4; \
            }                                                               \
        }                                                                   \
    }

#define COMPUTE(BF)                                                         \
    {                                                                       \
        _Pragma("unroll")                                                   \
        for (int j = 0; j < CK; ++j) {                                      \
            const float* fr   = &f_lds[BF][j][ty * 128 + w0];               \
            const float* srow = &s_lds[BF][4 + j * SROW + ty * 128 + w0];   \
            float4 fv4 = *(const float4*)fr;                                \
            float4 a0  = *(const float4*)(srow - 4);                        \
            float4 a1  = *(const float4*)(srow);                            \
            float4 a2  = *(const float4*)(srow + 4);                        \
            if (tx == 0)  a0 = zero4;                                       \
            if (tx == 31) a2 = zero4;                                       \
            float fv[RW] = {fv4.x, fv4.y, fv4.z, fv4.w};                    \
            float s[12]  = {a0.x, a0.y, a0.z, a0.w,                         \
                            a1.x, a1.y, a1.z, a1.w,                         \
                            a2.x, a2.y, a2.z, a2.w};                        \
            _Pragma("unroll")                                               \
            for (int dx = 0; dx < MO; ++dx)                                 \
                _Pragma("unroll")                                           \
                for (int p = 0; p < RW; ++p)                                \
                    acc[dx][p] += fv[p] * s[p + dx];                        \
        }                                                                   \
    }

    STAGE(0, 0)
    __syncthreads();
    for (int k = 0; k < NCK; ++k) {
        if (k + 1 < NCK) STAGE(k + 1, (k + 1) & 1)  // in flight during compute
        COMPUTE(k & 1)
        __syncthreads();   // drains chunk k+1's loads (aged ~500cyc) + reuse
    }
#undef STAGE
#undef COMPUTE

    const float inv = 1.0f / (float)C;
    float* obase = out + ((size_t)b * (MO * MO) + (size_t)dy * MO) * HW
                       + (size_t)h * W + w0;
#pragma unroll
    for (int dx = 0; dx < MO; ++dx) {
        float4 v = make_float4(acc[dx][0] * inv, acc[dx][1] * inv,
                               acc[dx][2] * inv, acc[dx][3] * inv);
        *(float4*)(obase + (size_t)dx * HW) = v;
    }
}

extern "C" void kernel_launch(void* const* d_in, const int* in_sizes, int n_in,
                              void* d_out, int out_size, void* d_ws, size_t ws_size,
                              hipStream_t stream) {
    const float* first  = (const float*)d_in[0];
    const float* second = (const float*)d_in[1];
    float* out = (float*)d_out;

    dim3 grid(32 * MO * B);     // 2304 blocks, 1-D for XCD swizzle decode
    dim3 block(32, TY);         // 128 threads = 2 waves
    corr_kernel<<<grid, block, 0, stream>>>(first, second, out);
}